// Round 10
// baseline (253.466 us; speedup 1.0000x reference)
//
#include <hip/hip_runtime.h>
#include <cstdint>
#include <cstddef>

typedef unsigned short u16;
typedef __attribute__((ext_vector_type(8))) __bf16 bf16x8;
typedef __attribute__((ext_vector_type(4))) float f32x4;
typedef __attribute__((ext_vector_type(4))) uint32_t u32x4;

#define B_ 4
#define N_ 4096
#define M_ 1024
#define QD_ 1024
#define CD_ 768
#define H_ 8
#define DH_ 64
#define INNER_ 512  // H_*DH_

// -------- helpers --------
__device__ __forceinline__ u16 f2bf(float f) {
  uint32_t u = __builtin_bit_cast(uint32_t, f);
  u += 0x7fffu + ((u >> 16) & 1u);  // RNE
  return (u16)(u >> 16);
}

__device__ __forceinline__ uint32_t pk2bf(float a, float b) {
#if __has_builtin(__builtin_amdgcn_cvt_pk_bf16_f32)
  typedef __attribute__((ext_vector_type(2))) __bf16 bf16x2;
  bf16x2 r = __builtin_amdgcn_cvt_pk_bf16_f32(a, b);
  return __builtin_bit_cast(uint32_t, r);
#elif __has_builtin(__builtin_amdgcn_perm)
  uint32_t ua = __builtin_bit_cast(uint32_t, a) + 0x8000u;
  uint32_t ub = __builtin_bit_cast(uint32_t, b) + 0x8000u;
  return __builtin_amdgcn_perm(ub, ua, 0x07060302u);
#else
  return (uint32_t)f2bf(a) | ((uint32_t)f2bf(b) << 16);
#endif
}

__device__ __forceinline__ void load_lds_16B(const void* g, void* l) {
  __builtin_amdgcn_global_load_lds(
      (__attribute__((address_space(1))) void*)(void*)g,
      (__attribute__((address_space(3))) void*)l, 16, 0, 0);
}

__device__ __forceinline__ bf16x8 ldfrag(const u16* p) {
  return __builtin_bit_cast(bf16x8, *(const uint4*)p);
}

__device__ __forceinline__ uint4 pk8(float4 a, float4 b) {
  uint4 p;
  p.x = pk2bf(a.x, a.y); p.y = pk2bf(a.z, a.w);
  p.z = pk2bf(b.x, b.y); p.w = pk2bf(b.z, b.w);
  return p;
}

// -------- merged weight transposes: 4 configs in one launch --------
__global__ __launch_bounds__(256) void transpose_all(const float* __restrict__ Wq,
                                                     const float* __restrict__ Wk,
                                                     const float* __restrict__ Wv,
                                                     const float* __restrict__ Wo,
                                                     u16* __restrict__ wqT,
                                                     u16* __restrict__ wkvT,
                                                     u16* __restrict__ woT,
                                                     float cl2) {
  __shared__ float tile[32][33];
  const int bid = blockIdx.x;
  const float* in; u16* out; int R, C; float scale; int bx, by;
  if (bid < 512)       { int r = bid;        in = Wq; out = wqT;  R = 1024; C = 512;  scale = 1.f; bx = r & 15; by = r >> 4; }
  else if (bid < 896)  { int r = bid - 512;  in = Wk; out = wkvT; R = 768;  C = 512;  scale = cl2; bx = r & 15; by = r >> 4; }
  else if (bid < 1280) { int r = bid - 896;  in = Wv; out = wkvT + (size_t)512 * 768; R = 768; C = 512; scale = 1.f; bx = r & 15; by = r >> 4; }
  else                 { int r = bid - 1280; in = Wo; out = woT;  R = 512;  C = 1024; scale = 1.f; bx = r & 31; by = r >> 5; }
  int tx = threadIdx.x & 31, ty = threadIdx.x >> 5;
  int c0 = bx * 32, r0 = by * 32;
#pragma unroll
  for (int j = 0; j < 4; j++)
    tile[ty + j * 8][tx] = in[(size_t)(r0 + ty + j * 8) * C + c0 + tx];
  __syncthreads();
#pragma unroll
  for (int j = 0; j < 4; j++)
    out[(size_t)(c0 + ty + j * 8) * R + r0 + tx] = f2bf(tile[tx][ty + j * 8] * scale);
}

// -------- 128x128 dbuf GEMM, BK=64, A = fp32 fused-cast, XOR-swizzled LDS ----
// (unchanged from r9: conflicts=0 verified; remaining cost is the __syncthreads
// vmcnt drain -- to be addressed after the counted-vmcnt scheme is proven on
// the out-proj kernel below, whose pure-gload staging has a clean vmcnt count.)
__global__ __launch_bounds__(256) void gemm_bt_f32a(const float* __restrict__ A,
                                                    const u16* __restrict__ Bt,
                                                    u16* __restrict__ Cout,
                                                    int M, int N, int K,
                                                    u16* __restrict__ Kc) {
  __shared__ u16 As[2][128 * 64];  // 2 x 16 KB
  __shared__ u16 Bs[2][128 * 64];  // 2 x 16 KB
  const int t = threadIdx.x;
  const int nwg = gridDim.x * gridDim.y;
  const int lin = blockIdx.y * gridDim.x + blockIdx.x;
  const int chunk = nwg >> 3;
  const int swz = (lin & 7) * chunk + (lin >> 3);
  const int bx = swz % gridDim.x, by = swz / gridDim.x;
  const int m0 = by * 128, n0 = bx * 128;
  const int w = t >> 6, l = t & 63, lr = l & 15, qd = l >> 4;
  const int wm = (w >> 1) * 64, wn = (w & 1) * 64;
  f32x4 acc[4][4] = {};

  const int srow[4] = { (t + 0) >> 3, (t + 256) >> 3, (t + 512) >> 3, (t + 768) >> 3 };
  const int sc8 = t & 7;

  {
#pragma unroll
    for (int i = 0; i < 4; i++) {
      const int row = srow[i], c8 = sc8;
      const float* s = A + (size_t)(m0 + row) * K + c8 * 8;
      float4 a0 = *(const float4*)s;
      float4 a1 = *(const float4*)(s + 4);
      *(uint4*)&As[0][row * 64 + ((c8 ^ (row & 7)) * 8)] = pk8(a0, a1);
      const int csrc = c8 ^ (row & 7);
      load_lds_16B(Bt + (size_t)(n0 + row) * K + csrc * 8, &Bs[0][(t + i * 256) * 8]);
    }
  }
  __syncthreads();

  const int NT = K >> 6;
  for (int kt = 0; kt < NT; kt++) {
    const int cur = kt & 1, nxt = cur ^ 1;
    float4 av0[4], av1[4];
    const bool pre = (kt + 1 < NT);
    if (pre) {
      const int kc = (kt + 1) * 64;
#pragma unroll
      for (int i = 0; i < 4; i++) {
        const int row = srow[i], c8 = sc8;
        const float* s = A + (size_t)(m0 + row) * K + kc + c8 * 8;
        av0[i] = *(const float4*)s;
        av1[i] = *(const float4*)(s + 4);
        const int csrc = c8 ^ (row & 7);
        load_lds_16B(Bt + (size_t)(n0 + row) * K + kc + csrc * 8, &Bs[nxt][(t + i * 256) * 8]);
      }
    }
#pragma unroll
    for (int ks = 0; ks < 2; ks++) {
      const int cs = ((ks * 4 + qd) ^ (lr & 7)) * 8;
      bf16x8 af[4], bf[4];
#pragma unroll
      for (int i = 0; i < 4; i++) af[i] = ldfrag(&As[cur][(wm + i * 16 + lr) * 64 + cs]);
#pragma unroll
      for (int j = 0; j < 4; j++) bf[j] = ldfrag(&Bs[cur][(wn + j * 16 + lr) * 64 + cs]);
#pragma unroll
      for (int mi = 0; mi < 4; mi++)
#pragma unroll
        for (int ni = 0; ni < 4; ni++)
          acc[mi][ni] = __builtin_amdgcn_mfma_f32_16x16x32_bf16(af[mi], bf[ni], acc[mi][ni], 0, 0, 0);
    }
    if (pre) {
#pragma unroll
      for (int i = 0; i < 4; i++) {
        const int row = srow[i], c8 = sc8;
        *(uint4*)&As[nxt][row * 64 + ((c8 ^ (row & 7)) * 8)] = pk8(av0[i], av1[i]);
      }
    }
    __syncthreads();
  }

  const bool kmode = (Kc != nullptr) && (n0 < 512);
  if (kmode) {
#pragma unroll
    for (int mi = 0; mi < 4; mi++)
#pragma unroll
      for (int ni = 0; ni < 4; ni++) {
        int col = n0 + wn + ni * 16 + lr;
        int h = col >> 6, c = (col >> 3) & 7, d0 = col & 7;
#pragma unroll
        for (int r = 0; r < 4; r++) {
          int row = m0 + wm + mi * 16 + qd * 4 + r;
          int b = row >> 10, m = row & 1023;
          int kt8 = m >> 7, ml = m & 127;
          size_t off = (size_t)((b << 3) + h) * 65536 + kt8 * 8192 + c * 1024 + ml * 8 + d0;
          Kc[off] = f2bf(acc[mi][ni][r]);
        }
      }
  } else {
#pragma unroll
    for (int mi = 0; mi < 4; mi++)
#pragma unroll
      for (int ni = 0; ni < 4; ni++) {
        int row = m0 + wm + mi * 16 + qd * 4;
        int col = n0 + wn + ni * 16 + lr;
#pragma unroll
        for (int r = 0; r < 4; r++)
          Cout[(size_t)(row + r) * N + col] = f2bf(acc[mi][ni][r]);
      }
  }
}

// -------- 256x128 GEMM, counted-vmcnt pipeline (out projection) --------
// T3/T4 applied to the harness-proven skeleton: raw s_barrier + counted
// s_waitcnt vmcnt(3) replaces __syncthreads' vmcnt(0) drain, so the 3
// prefetch gload_lds issued in step kt stay in flight across the whole
// MFMA phase and are only waited at step kt+1 (~2-4k cyc later).
// Per-step: [issue stage3(nxt)] [vmcnt(3): cur's 3 oldest done] [s_barrier]
// [ds_read cur + MFMA] [lgkmcnt(0)] [s_barrier: nxt-old reads done ->
// next iter may overwrite]. 2-buffer safety: gload(nxt) at kt is issued
// AFTER kt-1's barrier#2, which guaranteed all waves finished reading
// nxt's previous contents. Control flow wave-uniform (no divergence on kt).
// "memory"-clobbered asm fences stop the compiler hoisting LDS reads across
// the waits; sched_barrier(0) pins the machine scheduler (rule 18 class).
__global__ __launch_bounds__(512) void gemm256x128_bt(const u16* __restrict__ A,
                                                      const u16* __restrict__ Bt,
                                                      float* __restrict__ Cout,
                                                      int M, int N, int K,
                                                      const float* __restrict__ bias) {
  __shared__ u16 As[2][256 * 32];
  __shared__ u16 Bs[2][128 * 32];
  const int t = threadIdx.x;
  const int w = t >> 6, l = t & 63, lr = l & 15, qd = l >> 4;
  const int mw = w >> 1, nw2 = w & 1;
  const int nwg = gridDim.x * gridDim.y;
  const int lin = blockIdx.y * gridDim.x + blockIdx.x;
  const int chunk = nwg >> 3;
  const int swz = (lin & 7) * chunk + (lin >> 3);
  const int bx = swz % gridDim.x, by = swz / gridDim.x;
  const int m0 = by * 256, n0 = bx * 128;
  f32x4 acc[4][4] = {};
  const u16* ga = A + (size_t)(m0 + (t >> 2)) * K + (t & 3) * 8;
  const u16* gb = Bt + (size_t)(n0 + (t >> 2)) * K + (t & 3) * 8;

  // prologue: stage K-step 0 into buffer 0 (3 loads; waited inside the loop)
  load_lds_16B(ga, &As[0][t * 8]);
  load_lds_16B(ga + (size_t)128 * K, &As[0][(512 + t) * 8]);
  load_lds_16B(gb, &Bs[0][t * 8]);

  const int NT = K >> 5;
  for (int kt = 0; kt < NT; kt++) {
    const int cur = kt & 1, nxt = cur ^ 1;
    const bool pre = (kt + 1 < NT);
    if (pre) {
      const int kc = (kt + 1) * 32;
      load_lds_16B(ga + kc, &As[nxt][t * 8]);
      load_lds_16B(ga + kc + (size_t)128 * K, &As[nxt][(512 + t) * 8]);
      load_lds_16B(gb + kc, &Bs[nxt][t * 8]);
    }
    // wait cur's 3 loads (oldest); keep nxt's 3 in flight
    if (pre) asm volatile("s_waitcnt vmcnt(3)" ::: "memory");
    else     asm volatile("s_waitcnt vmcnt(0)" ::: "memory");
    __builtin_amdgcn_s_barrier();
    __builtin_amdgcn_sched_barrier(0);

    bf16x8 af[4], bf[4];
#pragma unroll
    for (int i = 0; i < 4; i++) af[i] = ldfrag(&As[cur][(mw * 64 + i * 16 + lr) * 32 + qd * 8]);
#pragma unroll
    for (int j = 0; j < 4; j++) bf[j] = ldfrag(&Bs[cur][(nw2 * 64 + j * 16 + lr) * 32 + qd * 8]);
#pragma unroll
    for (int mi = 0; mi < 4; mi++)
#pragma unroll
      for (int ni = 0; ni < 4; ni++)
        acc[mi][ni] = __builtin_amdgcn_mfma_f32_16x16x32_bf16(af[mi], bf[ni], acc[mi][ni], 0, 0, 0);

    // all this wave's ds_reads retired -> after barrier, buffer cur may be overwritten
    asm volatile("s_waitcnt lgkmcnt(0)" ::: "memory");
    __builtin_amdgcn_s_barrier();
  }

#pragma unroll
  for (int mi = 0; mi < 4; mi++)
#pragma unroll
    for (int ni = 0; ni < 4; ni++) {
      int row = m0 + mw * 64 + mi * 16 + qd * 4;
      int col = n0 + nw2 * 64 + ni * 16 + lr;
#pragma unroll
      for (int r = 0; r < 4; r++)
        Cout[(size_t)(row + r) * N + col] = acc[mi][ni][r] + bias[col];
    }
}

// -------- V-only repack: KVp cols 512..1023 -> Vtc[bh][kt=8][sc=16][d=64][8] --------
__global__ __launch_bounds__(256) void repack_v(const u16* __restrict__ KVp,
                                                u16* __restrict__ Vtc) {
  int idx = blockIdx.x * 256 + threadIdx.x;
  int bh = idx >> 13, rest = idx & 8191;
  int kt = rest >> 10, sc = (rest >> 6) & 15, d = rest & 63;
  int b = bh >> 3, h = bh & 7;
  int g = sc >> 3, ksl = (sc >> 2) & 1, qd = sc & 3;
  ushort4 lo, hi;
  const u16* src = KVp + (size_t)(b * M_) * 1024 + 512 + h * 64 + d;
  int jb = kt * 128 + g * 64 + ksl * 16 + qd * 4;
  lo.x = src[(size_t)(jb + 0) * 1024];
  lo.y = src[(size_t)(jb + 1) * 1024];
  lo.z = src[(size_t)(jb + 2) * 1024];
  lo.w = src[(size_t)(jb + 3) * 1024];
  hi.x = src[(size_t)(jb + 32) * 1024];
  hi.y = src[(size_t)(jb + 33) * 1024];
  hi.z = src[(size_t)(jb + 34) * 1024];
  hi.w = src[(size_t)(jb + 35) * 1024];
  u16* dst = Vtc + (size_t)idx * 8;
  *(ushort4*)dst = lo;
  *(ushort4*)(dst + 4) = hi;
}

// -------- flash attention v4 (r4-proven: Kc/Vtc, dbuf LDS, (256,2)) --------
__global__ __launch_bounds__(256, 2) void attn_kernel(const u16* __restrict__ Qp,
                                                      const u16* __restrict__ Kc,
                                                      const u16* __restrict__ Vtc,
                                                      u16* __restrict__ Og) {
  __shared__ u16 Ks2[2][8192];
  __shared__ u16 Vts2[2][8192];
  const int t = threadIdx.x;
  const int w = t >> 6, l = t & 63, lr = l & 15, qd = l >> 4;
  const int nwg = gridDim.x * gridDim.y;
  const int lin = blockIdx.y * gridDim.x + blockIdx.x;
  const int chunk = nwg >> 3;
  const int swz = (lin & 7) * chunk + (lin >> 3);
  const int qt = swz % gridDim.x, bh = swz / gridDim.x;
  const int b = bh >> 3, h = bh & 7;

  const size_t qbase = ((size_t)(b * N_ + qt * 256 + w * 64)) * INNER_ + h * DH_;
  bf16x8 qf[4][2];
#pragma unroll
  for (int qt2 = 0; qt2 < 4; qt2++)
#pragma unroll
    for (int dh = 0; dh < 2; dh++)
      qf[qt2][dh] = __builtin_bit_cast(bf16x8,
          *(const uint4*)(Qp + qbase + (size_t)(qt2 * 16 + lr) * INNER_ + dh * 32 + qd * 8));

  f32x4 oacc[4][4] = {};
  f32x4 lacc[4] = {};
  const u16* ksrc0 = Kc + (size_t)bh * 65536;
  const u16* vsrc0 = Vtc + (size_t)bh * 65536;

  u32x4 onesw;
  onesw[0] = 0x3F803F80u; onesw[1] = 0x3F803F80u; onesw[2] = 0x3F803F80u; onesw[3] = 0x3F803F80u;
  const bf16x8 onesf = __builtin_bit_cast(bf16x8, onesw);

#pragma unroll
  for (int i = 0; i < 4; i++) load_lds_16B(ksrc0 + (i * 256 + t) * 8, &Ks2[0][(i * 256 + t) * 8]);
#pragma unroll
  for (int i = 0; i < 4; i++) load_lds_16B(vsrc0 + (i * 256 + t) * 8, &Vts2[0][(i * 256 + t) * 8]);
  __syncthreads();

  for (int kt = 0; kt < 8; kt++) {
    const int cur = kt & 1, nxt = cur ^ 1;
    if (kt < 7) {
      const u16* kn = ksrc0 + (kt + 1) * 8192;
      const u16* vn = vsrc0 + (kt + 1) * 8192;
#pragma unroll
      for (int i = 0; i < 4; i++) load_lds_16B(kn + (i * 256 + t) * 8, &Ks2[nxt][(i * 256 + t) * 8]);
#pragma unroll
      for (int i = 0; i < 4; i++) load_lds_16B(vn + (i * 256 + t) * 8, &Vts2[nxt][(i * 256 + t) * 8]);
    }
    const u16* Ksc = Ks2[cur];
    const u16* Vsc = Vts2[cur];

#pragma unroll
    for (int g = 0; g < 2; g++) {
      f32x4 sacc[4][4] = {};
#pragma unroll
      for (int jt = 0; jt < 4; jt++)
#pragma unroll
        for (int dh = 0; dh < 2; dh++) {
          bf16x8 kf = ldfrag(&Ksc[(dh * 4 + qd) * 1024 + (g * 64 + jt * 16 + lr) * 8]);
#pragma unroll
          for (int qt2 = 0; qt2 < 4; qt2++)
            sacc[jt][qt2] = __builtin_amdgcn_mfma_f32_16x16x32_bf16(kf, qf[qt2][dh], sacc[jt][qt2], 0, 0, 0);
        }
#pragma unroll
      for (int jt = 0; jt < 4; jt++)
#pragma unroll
        for (int qt2 = 0; qt2 < 4; qt2++)
#pragma unroll
          for (int r = 0; r < 4; r++)
            sacc[jt][qt2][r] = __builtin_amdgcn_exp2f(sacc[jt][qt2][r]);
      u32x4 pk[4][2];
#pragma unroll
      for (int qt2 = 0; qt2 < 4; qt2++)
#pragma unroll
        for (int ksl = 0; ksl < 2; ksl++)
#pragma unroll
          for (int v = 0; v < 4; v++) {
            int jt = (v >> 1) * 2 + ksl, r = (v & 1) * 2;
            pk[qt2][ksl][v] = pk2bf(sacc[jt][qt2][r], sacc[jt][qt2][r + 1]);
          }
#pragma unroll
      for (int ksl = 0; ksl < 2; ksl++) {
#pragma unroll
        for (int dt = 0; dt < 4; dt++) {
          bf16x8 vf = ldfrag(&Vsc[(g * 8 + ksl * 4 + qd) * 512 + (dt * 16 + lr) * 8]);
#pragma unroll
          for (int qt2 = 0; qt2 < 4; qt2++)
            oacc[qt2][dt] = __builtin_amdgcn_mfma_f32_16x16x32_bf16(
                vf, __builtin_bit_cast(bf16x8, pk[qt2][ksl]), oacc[qt2][dt], 0, 0, 0);
        }
#pragma unroll
        for (int qt2 = 0; qt2 < 4; qt2++)
          lacc[qt2] = __builtin_amdgcn_mfma_f32_16x16x32_bf16(
              onesf, __builtin_bit_cast(bf16x8, pk[qt2][ksl]), lacc[qt2], 0, 0, 0);
      }
    }
    __syncthreads();
  }

#pragma unroll
  for (int qt2 = 0; qt2 < 4; qt2++) {
    float inv = 1.f / lacc[qt2][0];
    int q = qt * 256 + w * 64 + qt2 * 16 + lr;
    size_t base = ((size_t)(b * N_ + q)) * INNER_ + h * DH_ + qd * 4;
#pragma unroll
    for (int dt = 0; dt < 4; dt++) {
      uint2 o;
      o.x = pk2bf(oacc[qt2][dt][0] * inv, oacc[qt2][dt][1] * inv);
      o.y = pk2bf(oacc[qt2][dt][2] * inv, oacc[qt2][dt][3] * inv);
      *(uint2*)(Og + base + dt * 16) = o;
    }
  }
}

extern "C" void kernel_launch(void* const* d_in, const int* in_sizes, int n_in,
                              void* d_out, int out_size, void* d_ws, size_t ws_size,
                              hipStream_t stream) {
  const float* x   = (const float*)d_in[0];
  const float* ctx = (const float*)d_in[1];
  const float* Wq  = (const float*)d_in[2];
  const float* Wk  = (const float*)d_in[3];
  const float* Wv  = (const float*)d_in[4];
  const float* Wo  = (const float*)d_in[5];
  const float* bo  = (const float*)d_in[6];
  float* out = (float*)d_out;

  const float cl2 = 0.18033688011112042f;  // DH^-0.5 * log2(e), folded into WkT

  // workspace layout (u16 elements), ~46 MB
  u16* wqT  = (u16*)d_ws;                   // 512 x 1024
  u16* wkvT = wqT  + (size_t)512 * 1024;    // 1024 x 768
  u16* woT  = wkvT + (size_t)1024 * 768;    // 1024 x 512
  u16* Qp   = woT  + (size_t)1024 * 512;    // 16384 x 512
  u16* Kc   = Qp   + (size_t)16384 * 512;   // 32 x 65536
  u16* Vtc  = Kc   + (size_t)32 * 65536;    // 32 x 65536
  u16* Og   = Vtc  + (size_t)32 * 65536;    // 16384 x 512
  u16* KVp  = Og;                           // 4096 x 1024 (read by repack_v BEFORE attn writes Og)

  // 1) all weight transposes in one launch
  transpose_all<<<1792, 256, 0, stream>>>(Wq, Wk, Wv, Wo, wqT, wkvT, woT, cl2);

  // 2) projections, BK=64 swizzled f32a GEMM
  gemm_bt_f32a<<<dim3(4, 128), 256, 0, stream>>>(x, wqT, Qp, 16384, 512, 1024, nullptr);
  gemm_bt_f32a<<<dim3(8, 32), 256, 0, stream>>>(ctx, wkvT, KVp, 4096, 1024, 768, Kc);
  repack_v<<<1024, 256, 0, stream>>>(KVp, Vtc);

  // 3) attention
  attn_kernel<<<dim3(16, 32), 256, 0, stream>>>(Qp, Kc, Vtc, Og);

  // 4) out projection: counted-vmcnt pipelined GEMM (fp32 + bias)
  gemm256x128_bt<<<dim3(8, 64), 512, 0, stream>>>(Og, woT, out, 16384, 1024, 512, bo);
}

// Round 12
// 245.333 us; speedup vs baseline: 1.0332x; 1.0332x over previous
//
#include <hip/hip_runtime.h>
#include <cstdint>
#include <cstddef>

typedef unsigned short u16;
typedef __attribute__((ext_vector_type(8))) __bf16 bf16x8;
typedef __attribute__((ext_vector_type(4))) float f32x4;
typedef __attribute__((ext_vector_type(4))) uint32_t u32x4;

#define B_ 4
#define N_ 4096
#define M_ 1024
#define QD_ 1024
#define CD_ 768
#define H_ 8
#define DH_ 64
#define INNER_ 512  // H_*DH_

// -------- helpers --------
__device__ __forceinline__ u16 f2bf(float f) {
  uint32_t u = __builtin_bit_cast(uint32_t, f);
  u += 0x7fffu + ((u >> 16) & 1u);  // RNE
  return (u16)(u >> 16);
}

__device__ __forceinline__ uint32_t pk2bf(float a, float b) {
#if __has_builtin(__builtin_amdgcn_cvt_pk_bf16_f32)
  typedef __attribute__((ext_vector_type(2))) __bf16 bf16x2;
  bf16x2 r = __builtin_amdgcn_cvt_pk_bf16_f32(a, b);
  return __builtin_bit_cast(uint32_t, r);
#elif __has_builtin(__builtin_amdgcn_perm)
  uint32_t ua = __builtin_bit_cast(uint32_t, a) + 0x8000u;
  uint32_t ub = __builtin_bit_cast(uint32_t, b) + 0x8000u;
  return __builtin_amdgcn_perm(ub, ua, 0x07060302u);
#else
  return (uint32_t)f2bf(a) | ((uint32_t)f2bf(b) << 16);
#endif
}

__device__ __forceinline__ void load_lds_16B(const void* g, void* l) {
  __builtin_amdgcn_global_load_lds(
      (__attribute__((address_space(1))) void*)(void*)g,
      (__attribute__((address_space(3))) void*)l, 16, 0, 0);
}

__device__ __forceinline__ bf16x8 ldfrag(const u16* p) {
  return __builtin_bit_cast(bf16x8, *(const uint4*)p);
}

__device__ __forceinline__ uint4 pk8(float4 a, float4 b) {
  uint4 p;
  p.x = pk2bf(a.x, a.y); p.y = pk2bf(a.z, a.w);
  p.z = pk2bf(b.x, b.y); p.w = pk2bf(b.z, b.w);
  return p;
}

// -------- merged weight transposes: 4 configs in one launch --------
__global__ __launch_bounds__(256) void transpose_all(const float* __restrict__ Wq,
                                                     const float* __restrict__ Wk,
                                                     const float* __restrict__ Wv,
                                                     const float* __restrict__ Wo,
                                                     u16* __restrict__ wqT,
                                                     u16* __restrict__ wkvT,
                                                     u16* __restrict__ woT,
                                                     float cl2) {
  __shared__ float tile[32][33];
  const int bid = blockIdx.x;
  const float* in; u16* out; int R, C; float scale; int bx, by;
  if (bid < 512)       { int r = bid;        in = Wq; out = wqT;  R = 1024; C = 512;  scale = 1.f; bx = r & 15; by = r >> 4; }
  else if (bid < 896)  { int r = bid - 512;  in = Wk; out = wkvT; R = 768;  C = 512;  scale = cl2; bx = r & 15; by = r >> 4; }
  else if (bid < 1280) { int r = bid - 896;  in = Wv; out = wkvT + (size_t)512 * 768; R = 768; C = 512; scale = 1.f; bx = r & 15; by = r >> 4; }
  else                 { int r = bid - 1280; in = Wo; out = woT;  R = 512;  C = 1024; scale = 1.f; bx = r & 31; by = r >> 5; }
  int tx = threadIdx.x & 31, ty = threadIdx.x >> 5;
  int c0 = bx * 32, r0 = by * 32;
#pragma unroll
  for (int j = 0; j < 4; j++)
    tile[ty + j * 8][tx] = in[(size_t)(r0 + ty + j * 8) * C + c0 + tx];
  __syncthreads();
#pragma unroll
  for (int j = 0; j < 4; j++)
    out[(size_t)(c0 + ty + j * 8) * R + r0 + tx] = f2bf(tile[tx][ty + j * 8] * scale);
}

// -------- fused projection GEMM: Q-proj (blocks 0..511) + KV-proj (512..767) --------
// One dispatch so the two independent, latency-bound GEMMs interleave on the
// machine. Structure identical to the r9/r10 harness-proven gemm_bt_f32a
// (64 KiB LDS, dbuf + __syncthreads, XOR swizzle, conflicts=0 measured);
// additions are register-only: block-range branch + packed epilogues.
// Epilogues: Q -> Qp row-major; KV n0<512 -> Kc packed (r8-verified);
// KV n0>=512 -> Vtc packed (replaces repack_v; inverse mapping re-derived:
// off = bh*65536 + kt*8192 + sc*512 + d*8 + e, s=m&63, hi=s>>5, ksl=(s>>4)&1,
// qdv=(s>>2)&3, rr=s&3, e=rr+4*hi, sc=(m>>6 & 1)*8 + ksl*4 + qdv).
__global__ __launch_bounds__(256) void gemm_fused_proj(const float* __restrict__ x,
                                                       const float* __restrict__ ctx,
                                                       const u16* __restrict__ wqT,
                                                       const u16* __restrict__ wkvT,
                                                       u16* __restrict__ Qp,
                                                       u16* __restrict__ Kc,
                                                       u16* __restrict__ Vtc) {
  __shared__ u16 As[2][128 * 64];  // 2 x 16 KB
  __shared__ u16 Bs[2][128 * 64];  // 2 x 16 KB
  const int t = threadIdx.x;
  const bool isQ = (blockIdx.x < 512);
  const float* A; const u16* Bt; int K, lin, nwg, gx;
  if (isQ) { A = x;   Bt = wqT;  K = 1024; lin = blockIdx.x;       nwg = 512; gx = 4; }
  else     { A = ctx; Bt = wkvT; K = 768;  lin = blockIdx.x - 512; nwg = 256; gx = 8; }
  const int chunk = nwg >> 3;
  const int swz = (lin & 7) * chunk + (lin >> 3);
  const int bx = swz % gx, by = swz / gx;
  const int m0 = by * 128, n0 = bx * 128;
  const int w = t >> 6, l = t & 63, lr = l & 15, qd = l >> 4;
  const int wm = (w >> 1) * 64, wn = (w & 1) * 64;
  f32x4 acc[4][4] = {};

  const int srow[4] = { (t + 0) >> 3, (t + 256) >> 3, (t + 512) >> 3, (t + 768) >> 3 };
  const int sc8 = t & 7;

  // prologue: stage K-step 0 into buffer 0
  {
#pragma unroll
    for (int i = 0; i < 4; i++) {
      const int row = srow[i], c8 = sc8;
      const float* s = A + (size_t)(m0 + row) * K + c8 * 8;
      float4 a0 = *(const float4*)s;
      float4 a1 = *(const float4*)(s + 4);
      *(uint4*)&As[0][row * 64 + ((c8 ^ (row & 7)) * 8)] = pk8(a0, a1);
      const int csrc = c8 ^ (row & 7);
      load_lds_16B(Bt + (size_t)(n0 + row) * K + csrc * 8, &Bs[0][(t + i * 256) * 8]);
    }
  }
  __syncthreads();

  const int NT = K >> 6;
  for (int kt = 0; kt < NT; kt++) {
    const int cur = kt & 1, nxt = cur ^ 1;
    float4 av0[4], av1[4];
    const bool pre = (kt + 1 < NT);
    if (pre) {
      const int kc = (kt + 1) * 64;
#pragma unroll
      for (int i = 0; i < 4; i++) {
        const int row = srow[i], c8 = sc8;
        const float* s = A + (size_t)(m0 + row) * K + kc + c8 * 8;
        av0[i] = *(const float4*)s;
        av1[i] = *(const float4*)(s + 4);
        const int csrc = c8 ^ (row & 7);
        load_lds_16B(Bt + (size_t)(n0 + row) * K + kc + csrc * 8, &Bs[nxt][(t + i * 256) * 8]);
      }
    }
#pragma unroll
    for (int ks = 0; ks < 2; ks++) {
      const int cs = ((ks * 4 + qd) ^ (lr & 7)) * 8;
      bf16x8 af[4], bf[4];
#pragma unroll
      for (int i = 0; i < 4; i++) af[i] = ldfrag(&As[cur][(wm + i * 16 + lr) * 64 + cs]);
#pragma unroll
      for (int j = 0; j < 4; j++) bf[j] = ldfrag(&Bs[cur][(wn + j * 16 + lr) * 64 + cs]);
#pragma unroll
      for (int mi = 0; mi < 4; mi++)
#pragma unroll
        for (int ni = 0; ni < 4; ni++)
          acc[mi][ni] = __builtin_amdgcn_mfma_f32_16x16x32_bf16(af[mi], bf[ni], acc[mi][ni], 0, 0, 0);
    }
    if (pre) {
#pragma unroll
      for (int i = 0; i < 4; i++) {
        const int row = srow[i], c8 = sc8;
        *(uint4*)&As[nxt][row * 64 + ((c8 ^ (row & 7)) * 8)] = pk8(av0[i], av1[i]);
      }
    }
    __syncthreads();
  }

  if (isQ) {
#pragma unroll
    for (int mi = 0; mi < 4; mi++)
#pragma unroll
      for (int ni = 0; ni < 4; ni++) {
        int row = m0 + wm + mi * 16 + qd * 4;
        int col = n0 + wn + ni * 16 + lr;
#pragma unroll
        for (int r = 0; r < 4; r++)
          Qp[(size_t)(row + r) * 512 + col] = f2bf(acc[mi][ni][r]);
      }
  } else if (n0 < 512) {
    // K projection -> Kc packed layout (r8-verified)
#pragma unroll
    for (int mi = 0; mi < 4; mi++)
#pragma unroll
      for (int ni = 0; ni < 4; ni++) {
        int col = n0 + wn + ni * 16 + lr;
        int h = col >> 6, c = (col >> 3) & 7, d0 = col & 7;
#pragma unroll
        for (int r = 0; r < 4; r++) {
          int row = m0 + wm + mi * 16 + qd * 4 + r;
          int b = row >> 10, m = row & 1023;
          int kt8 = m >> 7, ml = m & 127;
          size_t off = (size_t)((b << 3) + h) * 65536 + kt8 * 8192 + c * 1024 + ml * 8 + d0;
          Kc[off] = f2bf(acc[mi][ni][r]);
        }
      }
  } else {
    // V projection -> Vtc packed layout (replaces repack_v)
#pragma unroll
    for (int mi = 0; mi < 4; mi++)
#pragma unroll
      for (int ni = 0; ni < 4; ni++) {
        int col = n0 + wn + ni * 16 + lr;
        int cv = col - 512;
        int h = cv >> 6, d = cv & 63;
#pragma unroll
        for (int r = 0; r < 4; r++) {
          int row = m0 + wm + mi * 16 + qd * 4 + r;
          int b = row >> 10, m = row & 1023;
          int kt8 = m >> 7, mrem = m & 127;
          int g = mrem >> 6, s = mrem & 63;
          int hi = s >> 5, ksl = (s >> 4) & 1, qdv = (s >> 2) & 3, rr = s & 3;
          int e = rr + (hi << 2);
          int sc = g * 8 + ksl * 4 + qdv;
          size_t off = (size_t)((b << 3) + h) * 65536 + kt8 * 8192 + sc * 512 + d * 8 + e;
          Vtc[off] = f2bf(acc[mi][ni][r]);
        }
      }
  }
}

// -------- 256x128 dbuf GEMM, bf16 A (out projection, fp32 out + bias) --------
__global__ __launch_bounds__(512) void gemm256x128_bt(const u16* __restrict__ A,
                                                      const u16* __restrict__ Bt,
                                                      float* __restrict__ Cout,
                                                      int M, int N, int K,
                                                      const float* __restrict__ bias) {
  __shared__ u16 As[2][256 * 32];
  __shared__ u16 Bs[2][128 * 32];
  const int t = threadIdx.x;
  const int w = t >> 6, l = t & 63, lr = l & 15, qd = l >> 4;
  const int mw = w >> 1, nw2 = w & 1;
  const int nwg = gridDim.x * gridDim.y;
  const int lin = blockIdx.y * gridDim.x + blockIdx.x;
  const int chunk = nwg >> 3;
  const int swz = (lin & 7) * chunk + (lin >> 3);
  const int bx = swz % gridDim.x, by = swz / gridDim.x;
  const int m0 = by * 256, n0 = bx * 128;
  f32x4 acc[4][4] = {};
  const u16* ga = A + (size_t)(m0 + (t >> 2)) * K + (t & 3) * 8;
  const u16* gb = Bt + (size_t)(n0 + (t >> 2)) * K + (t & 3) * 8;

  load_lds_16B(ga, &As[0][t * 8]);
  load_lds_16B(ga + (size_t)128 * K, &As[0][(512 + t) * 8]);
  load_lds_16B(gb, &Bs[0][t * 8]);
  __syncthreads();

  const int NT = K >> 5;
  for (int kt = 0; kt < NT; kt++) {
    const int cur = kt & 1, nxt = cur ^ 1;
    if (kt + 1 < NT) {
      const int kc = (kt + 1) * 32;
      load_lds_16B(ga + kc, &As[nxt][t * 8]);
      load_lds_16B(ga + kc + (size_t)128 * K, &As[nxt][(512 + t) * 8]);
      load_lds_16B(gb + kc, &Bs[nxt][t * 8]);
    }
    bf16x8 af[4], bf[4];
#pragma unroll
    for (int i = 0; i < 4; i++) af[i] = ldfrag(&As[cur][(mw * 64 + i * 16 + lr) * 32 + qd * 8]);
#pragma unroll
    for (int j = 0; j < 4; j++) bf[j] = ldfrag(&Bs[cur][(nw2 * 64 + j * 16 + lr) * 32 + qd * 8]);
#pragma unroll
    for (int mi = 0; mi < 4; mi++)
#pragma unroll
      for (int ni = 0; ni < 4; ni++)
        acc[mi][ni] = __builtin_amdgcn_mfma_f32_16x16x32_bf16(af[mi], bf[ni], acc[mi][ni], 0, 0, 0);
    __syncthreads();
  }

#pragma unroll
  for (int mi = 0; mi < 4; mi++)
#pragma unroll
    for (int ni = 0; ni < 4; ni++) {
      int row = m0 + mw * 64 + mi * 16 + qd * 4;
      int col = n0 + nw2 * 64 + ni * 16 + lr;
#pragma unroll
      for (int r = 0; r < 4; r++)
        Cout[(size_t)(row + r) * N + col] = acc[mi][ni][r] + bias[col];
    }
}

// -------- flash attention v4 (r4-proven: Kc/Vtc, dbuf LDS, (256,2)) --------
__global__ __launch_bounds__(256, 2) void attn_kernel(const u16* __restrict__ Qp,
                                                      const u16* __restrict__ Kc,
                                                      const u16* __restrict__ Vtc,
                                                      u16* __restrict__ Og) {
  __shared__ u16 Ks2[2][8192];
  __shared__ u16 Vts2[2][8192];
  const int t = threadIdx.x;
  const int w = t >> 6, l = t & 63, lr = l & 15, qd = l >> 4;
  const int nwg = gridDim.x * gridDim.y;
  const int lin = blockIdx.y * gridDim.x + blockIdx.x;
  const int chunk = nwg >> 3;
  const int swz = (lin & 7) * chunk + (lin >> 3);
  const int qt = swz % gridDim.x, bh = swz / gridDim.x;
  const int b = bh >> 3, h = bh & 7;

  const size_t qbase = ((size_t)(b * N_ + qt * 256 + w * 64)) * INNER_ + h * DH_;
  bf16x8 qf[4][2];
#pragma unroll
  for (int qt2 = 0; qt2 < 4; qt2++)
#pragma unroll
    for (int dh = 0; dh < 2; dh++)
      qf[qt2][dh] = __builtin_bit_cast(bf16x8,
          *(const uint4*)(Qp + qbase + (size_t)(qt2 * 16 + lr) * INNER_ + dh * 32 + qd * 8));

  f32x4 oacc[4][4] = {};
  f32x4 lacc[4] = {};
  const u16* ksrc0 = Kc + (size_t)bh * 65536;
  const u16* vsrc0 = Vtc + (size_t)bh * 65536;

  u32x4 onesw;
  onesw[0] = 0x3F803F80u; onesw[1] = 0x3F803F80u; onesw[2] = 0x3F803F80u; onesw[3] = 0x3F803F80u;
  const bf16x8 onesf = __builtin_bit_cast(bf16x8, onesw);

#pragma unroll
  for (int i = 0; i < 4; i++) load_lds_16B(ksrc0 + (i * 256 + t) * 8, &Ks2[0][(i * 256 + t) * 8]);
#pragma unroll
  for (int i = 0; i < 4; i++) load_lds_16B(vsrc0 + (i * 256 + t) * 8, &Vts2[0][(i * 256 + t) * 8]);
  __syncthreads();

  for (int kt = 0; kt < 8; kt++) {
    const int cur = kt & 1, nxt = cur ^ 1;
    if (kt < 7) {
      const u16* kn = ksrc0 + (kt + 1) * 8192;
      const u16* vn = vsrc0 + (kt + 1) * 8192;
#pragma unroll
      for (int i = 0; i < 4; i++) load_lds_16B(kn + (i * 256 + t) * 8, &Ks2[nxt][(i * 256 + t) * 8]);
#pragma unroll
      for (int i = 0; i < 4; i++) load_lds_16B(vn + (i * 256 + t) * 8, &Vts2[nxt][(i * 256 + t) * 8]);
    }
    const u16* Ksc = Ks2[cur];
    const u16* Vsc = Vts2[cur];

#pragma unroll
    for (int g = 0; g < 2; g++) {
      f32x4 sacc[4][4] = {};
#pragma unroll
      for (int jt = 0; jt < 4; jt++)
#pragma unroll
        for (int dh = 0; dh < 2; dh++) {
          bf16x8 kf = ldfrag(&Ksc[(dh * 4 + qd) * 1024 + (g * 64 + jt * 16 + lr) * 8]);
#pragma unroll
          for (int qt2 = 0; qt2 < 4; qt2++)
            sacc[jt][qt2] = __builtin_amdgcn_mfma_f32_16x16x32_bf16(kf, qf[qt2][dh], sacc[jt][qt2], 0, 0, 0);
        }
#pragma unroll
      for (int jt = 0; jt < 4; jt++)
#pragma unroll
        for (int qt2 = 0; qt2 < 4; qt2++)
#pragma unroll
          for (int r = 0; r < 4; r++)
            sacc[jt][qt2][r] = __builtin_amdgcn_exp2f(sacc[jt][qt2][r]);
      u32x4 pk[4][2];
#pragma unroll
      for (int qt2 = 0; qt2 < 4; qt2++)
#pragma unroll
        for (int ksl = 0; ksl < 2; ksl++)
#pragma unroll
          for (int v = 0; v < 4; v++) {
            int jt = (v >> 1) * 2 + ksl, r = (v & 1) * 2;
            pk[qt2][ksl][v] = pk2bf(sacc[jt][qt2][r], sacc[jt][qt2][r + 1]);
          }
#pragma unroll
      for (int ksl = 0; ksl < 2; ksl++) {
#pragma unroll
        for (int dt = 0; dt < 4; dt++) {
          bf16x8 vf = ldfrag(&Vsc[(g * 8 + ksl * 4 + qd) * 512 + (dt * 16 + lr) * 8]);
#pragma unroll
          for (int qt2 = 0; qt2 < 4; qt2++)
            oacc[qt2][dt] = __builtin_amdgcn_mfma_f32_16x16x32_bf16(
                vf, __builtin_bit_cast(bf16x8, pk[qt2][ksl]), oacc[qt2][dt], 0, 0, 0);
        }
#pragma unroll
        for (int qt2 = 0; qt2 < 4; qt2++)
          lacc[qt2] = __builtin_amdgcn_mfma_f32_16x16x32_bf16(
              onesf, __builtin_bit_cast(bf16x8, pk[qt2][ksl]), lacc[qt2], 0, 0, 0);
      }
    }
    __syncthreads();
  }

#pragma unroll
  for (int qt2 = 0; qt2 < 4; qt2++) {
    float inv = 1.f / lacc[qt2][0];
    int q = qt * 256 + w * 64 + qt2 * 16 + lr;
    size_t base = ((size_t)(b * N_ + q)) * INNER_ + h * DH_ + qd * 4;
#pragma unroll
    for (int dt = 0; dt < 4; dt++) {
      uint2 o;
      o.x = pk2bf(oacc[qt2][dt][0] * inv, oacc[qt2][dt][1] * inv);
      o.y = pk2bf(oacc[qt2][dt][2] * inv, oacc[qt2][dt][3] * inv);
      *(uint2*)(Og + base + dt * 16) = o;
    }
  }
}

extern "C" void kernel_launch(void* const* d_in, const int* in_sizes, int n_in,
                              void* d_out, int out_size, void* d_ws, size_t ws_size,
                              hipStream_t stream) {
  const float* x   = (const float*)d_in[0];
  const float* ctx = (const float*)d_in[1];
  const float* Wq  = (const float*)d_in[2];
  const float* Wk  = (const float*)d_in[3];
  const float* Wv  = (const float*)d_in[4];
  const float* Wo  = (const float*)d_in[5];
  const float* bo  = (const float*)d_in[6];
  float* out = (float*)d_out;

  const float cl2 = 0.18033688011112042f;  // DH^-0.5 * log2(e), folded into WkT

  // workspace layout (u16 elements), ~38 MB (KVp eliminated)
  u16* wqT  = (u16*)d_ws;                   // 512 x 1024
  u16* wkvT = wqT  + (size_t)512 * 1024;    // 1024 x 768
  u16* woT  = wkvT + (size_t)1024 * 768;    // 1024 x 512
  u16* Qp   = woT  + (size_t)1024 * 512;    // 16384 x 512
  u16* Kc   = Qp   + (size_t)16384 * 512;   // 32 x 65536
  u16* Vtc  = Kc   + (size_t)32 * 65536;    // 32 x 65536
  u16* Og   = Vtc  + (size_t)32 * 65536;    // 16384 x 512

  // 1) all weight transposes in one launch
  transpose_all<<<1792, 256, 0, stream>>>(Wq, Wk, Wv, Wo, wqT, wkvT, woT, cl2);

  // 2) fused Q-proj + KV-proj (K and V written directly in packed layouts)
  gemm_fused_proj<<<768, 256, 0, stream>>>(x, ctx, wqT, wkvT, Qp, Kc, Vtc);

  // 3) attention
  attn_kernel<<<dim3(16, 32), 256, 0, stream>>>(Qp, Kc, Vtc, Og);

  // 4) out projection (fp32 + bias)
  gemm256x128_bt<<<dim3(8, 64), 512, 0, stream>>>(Og, woT, out, 16384, 1024, 512, bo);
}